// Round 4
// baseline (537.515 us; speedup 1.0000x reference)
//
#include <hip/hip_runtime.h>

typedef short bf16x8 __attribute__((ext_vector_type(8)));
typedef float f32x4 __attribute__((ext_vector_type(4)));

__device__ __forceinline__ unsigned short f2bf(float f) {
    union { float f; unsigned u; } a; a.f = f;
    unsigned u = a.u;
    u += 0x7fffu + ((u >> 16) & 1u);   // round-to-nearest-even
    return (unsigned short)(u >> 16);
}

__device__ __forceinline__ bf16x8 pack8(f32x4 v0, f32x4 v1) {
    bf16x8 r;
    r[0] = f2bf(v0[0]); r[1] = f2bf(v0[1]); r[2] = f2bf(v0[2]); r[3] = f2bf(v0[3]);
    r[4] = f2bf(v1[0]); r[5] = f2bf(v1[1]); r[6] = f2bf(v1[2]); r[7] = f2bf(v1[3]);
    return r;
}

__device__ __forceinline__ f32x4 mfma16(bf16x8 a, bf16x8 b, f32x4 c) {
    return __builtin_amdgcn_mfma_f32_16x16x32_bf16(a, b, c, 0, 0, 0);
}

// Expanded transposed weight: wt[n'][k'] = (n'%D==k'%D) ? w[k'/D][n'/D]*scale : 0
template<int D, int MUL>
__global__ void expand_w(const float* __restrict__ w, unsigned short* __restrict__ wt,
                         float scale) {
    const int n = blockIdx.x;      // 0..MUL*D-1
    const int k = threadIdx.x;     // 0..MUL*D-1
    float v = 0.0f;
    if (D == 1 || (n % D) == (k % D))
        v = w[(k / D) * MUL + (n / D)] * scale;
    wt[n * (MUL * D) + k] = f2bf(v);
}

// One irrep block, MT m-tiles (16 rows each) held in registers. Barrier-free.
// KP is square (K' == N'), so n-chunk count (pairs of n-tiles) == KP/32 == KS.
// xw = x + (z0+lr)*960 + q*8      (A-fragment base for this wave/lane)
// ow = out + (z0+q*4)*960 + lr    (C base for this wave/lane)
template<int KP, int OFF, int MT>
__device__ __forceinline__ void do_block(const float* __restrict__ xw,
                                         const unsigned short* __restrict__ wb,
                                         float* __restrict__ ow,
                                         int lr, int q) {
    constexpr int KS = KP / 32;

    // ---- A-fragments: global -> regs in MFMA layout (16 rows x 128B per pair) ----
    bf16x8 a[MT][KS];
    #pragma unroll
    for (int mt = 0; mt < MT; ++mt)
        #pragma unroll
        for (int ks = 0; ks < KS; ++ks) {
            const float* p = xw + mt * (16 * 960) + OFF + ks * 32;
            a[mt][ks] = pack8(*(const f32x4*)p, *(const f32x4*)(p + 4));
        }

    // ---- n-tile pairs: B' from L2, MFMA, direct paired (128B/row) stores ----
    const unsigned short* bp = wb + lr * KP + q * 8;
    #pragma unroll 1
    for (int c = 0; c < KS; ++c) {
        const unsigned short* b0p = bp + (c * 32 + 0)  * KP;   // n-tile 2c
        const unsigned short* b1p = bp + (c * 32 + 16) * KP;   // n-tile 2c+1
        f32x4 acc[MT][2];
        #pragma unroll
        for (int mt = 0; mt < MT; ++mt) {
            acc[mt][0] = (f32x4){0.f, 0.f, 0.f, 0.f};
            acc[mt][1] = (f32x4){0.f, 0.f, 0.f, 0.f};
        }
        #pragma unroll
        for (int ks = 0; ks < KS; ++ks) {
            bf16x8 b0 = *(const bf16x8*)(b0p + ks * 32);
            bf16x8 b1 = *(const bf16x8*)(b1p + ks * 32);
            #pragma unroll
            for (int mt = 0; mt < MT; ++mt) {
                acc[mt][0] = mfma16(a[mt][ks], b0, acc[mt][0]);
                acc[mt][1] = mfma16(a[mt][ks], b1, acc[mt][1]);
            }
        }
        #pragma unroll
        for (int mt = 0; mt < MT; ++mt)
            #pragma unroll
            for (int j = 0; j < 4; ++j) {
                float* po = ow + (mt * 16 + j) * 960 + OFF + c * 32;
                po[0]  = acc[mt][0][j];   // n-tile 2c   (64B seg, pairs to 128B)
                po[16] = acc[mt][1][j];   // n-tile 2c+1
            }
    }
}

__global__ __launch_bounds__(256)
void fused_linear(const float* __restrict__ x, const unsigned short* __restrict__ wt,
                  float* __restrict__ out) {
    const int tid  = threadIdx.x;
    const int lane = tid & 63;
    const int lr   = lane & 15;
    const int q    = lane >> 4;
    const long z0  = ((long)blockIdx.x * 4 + (tid >> 6)) * 32;   // 32 rows per wave

    const float* xw = x   + (z0 + lr) * 960 + q * 8;
    float*       ow = out + (z0 + q * 4) * 960 + lr;

    do_block<256,   0, 2>(xw, wt,          ow, lr, q);
    // block1 (K'=384): two 16-row passes to cap A-regs at 48
    do_block<384, 256, 1>(xw,            wt + 65536, ow,            lr, q);
    do_block<384, 256, 1>(xw + 16 * 960, wt + 65536, ow + 16 * 960, lr, q);
    do_block<320, 640, 2>(xw, wt + 212992, ow, lr, q);
}

extern "C" void kernel_launch(void* const* d_in, const int* in_sizes, int n_in,
                              void* d_out, int out_size, void* d_ws, size_t ws_size,
                              hipStream_t stream) {
    const float* x  = (const float*)d_in[0];
    const float* w0 = (const float*)d_in[1];
    const float* w1 = (const float*)d_in[2];
    const float* w2 = (const float*)d_in[3];
    float* out = (float*)d_out;
    unsigned short* wt = (unsigned short*)d_ws;  // needs 315392*2 = 630784 B scratch

    const int N = in_sizes[0] / 960;

    expand_w<1, 256><<<256, 256, 0, stream>>>(w0, wt,          0.0625f);
    expand_w<3, 128><<<384, 384, 0, stream>>>(w1, wt +  65536, 0.08838834764831845f);
    expand_w<5,  64><<<320, 320, 0, stream>>>(w2, wt + 212992, 0.125f);

    fused_linear<<<N / 128, 256, 0, stream>>>(x, wt, out);   // 4 waves/WG, 32 rows/wave
}

// Round 5
// 467.551 us; speedup vs baseline: 1.1496x; 1.1496x over previous
//
#include <hip/hip_runtime.h>

typedef short bf16x8 __attribute__((ext_vector_type(8)));
typedef float f32x4 __attribute__((ext_vector_type(4)));
typedef unsigned short u16t;

__device__ __forceinline__ u16t f2bf(float f) {
    union { float f; unsigned u; } a; a.f = f;
    unsigned u = a.u;
    u += 0x7fffu + ((u >> 16) & 1u);   // round-to-nearest-even
    return (u16t)(u >> 16);
}

__device__ __forceinline__ f32x4 mfma16(bf16x8 a, bf16x8 b, f32x4 c) {
    return __builtin_amdgcn_mfma_f32_16x16x32_bf16(a, b, c, 0, 0, 0);
}

// Pack W into MFMA-B-fragment-ready layout: frag F, lane l, elems j=0..7:
//   val = W[k][n]*scale, k = ks*32 + (l>>4)*8 + j, n = nt*16 + (l&15)
// Frag ids: block0: F = nt*8+ks (128); block1: 128 + n1t*4+ks (32); block2: 160 + n1t*2+ks (8).
// (Residue-independent: same W frag serves all m-components of an irrep.)
__global__ void pack_w(const float* __restrict__ w0, const float* __restrict__ w1,
                       const float* __restrict__ w2, u16t* __restrict__ wt) {
    const int F = blockIdx.x, l = threadIdx.x;
    const float* w; int MUL, nt, ks; float s;
    if (F < 128)      { w = w0; MUL = 256; s = 0.0625f;               nt = F >> 3;         ks = F & 7; }
    else if (F < 160) { w = w1; MUL = 128; s = 0.08838834764831845f;  nt = (F - 128) >> 2; ks = (F - 128) & 3; }
    else              { w = w2; MUL = 64;  s = 0.125f;                nt = (F - 160) >> 1; ks = (F - 160) & 1; }
    const int n  = nt * 16 + (l & 15);
    const int kb = ks * 32 + (l >> 4) * 8;
    u16t* o = wt + F * 512 + l * 8;
    #pragma unroll
    for (int j = 0; j < 8; ++j)
        o[j] = f2bf(w[(kb + j) * MUL + n] * s);
}

// strided bf16 gather from swizzled LDS row (stride in bytes: 6 for l=1, 10 for l=2)
__device__ __forceinline__ bf16x8 gatherA(const char* rb, int d0, int sw, int stride) {
    bf16x8 r;
    #pragma unroll
    for (int j = 0; j < 8; ++j)
        r[j] = *(const u16t*)(rb + ((d0 + stride * j) ^ sw));
    return r;
}

// One WG (512 thr = 8 waves) per CU; grid-stride over 16-row tiles.
// B-frags persistent in VGPRs (22 frags/wave). LDS: 2 x 16 rows x 2048B (64 KB), XOR-swizzled.
// One raw s_barrier per iteration; next-tile global loads in flight across it.
__global__ __launch_bounds__(512, 2)
void fused_linear(const float* __restrict__ x, const u16t* __restrict__ wt,
                  float* __restrict__ out, int tiles) {
    __shared__ __align__(16) u16t As[2][16][1024];   // 64 KB
    const int tid  = threadIdx.x;
    const int lane = tid & 63;
    const int wv   = tid >> 6;          // 0..7
    const int lr   = lane & 15;
    const int q    = lane >> 4;
    const int sw   = (lr & 7) << 4;     // read-side swizzle (lane-constant)

    // ---- persistent B fragments ----
    bf16x8 b0r[2][8];
    #pragma unroll
    for (int i = 0; i < 2; ++i)
        #pragma unroll
        for (int ks = 0; ks < 8; ++ks)
            b0r[i][ks] = *(const bf16x8*)(wt + (((2 * wv + i) * 8 + ks) * 512) + lane * 8);
    bf16x8 b1r[4];
    #pragma unroll
    for (int ks = 0; ks < 4; ++ks)
        b1r[ks] = *(const bf16x8*)(wt + ((128 + wv * 4 + ks) * 512) + lane * 8);
    const int rb2  = (wv < 4) ? 0 : 3;   // block2 residue base for this wave
    const int nR2  = (wv < 4) ? 3 : 2;   // residues handled (3+2 over wave pairs)
    const int n1t2 = wv & 3;
    bf16x8 b2r[2];
    #pragma unroll
    for (int ks = 0; ks < 2; ++ks)
        b2r[ks] = *(const bf16x8*)(wt + ((160 + n1t2 * 2 + ks) * 512) + lane * 8);

    f32x4 g[8];
    int tile = blockIdx.x;
    if (tile < tiles) {
        #pragma unroll
        for (int it = 0; it < 8; ++it) {
            int idx = tid + it * 512;
            int row = idx >> 8;
            int c4 = (idx & 255) * 4; if (c4 > 956) c4 = 956;
            g[it] = *(const f32x4*)(x + ((long)tile * 16 + row) * 960 + c4);
        }
    }

    for (int p = 0; tile < tiles; tile += gridDim.x, p ^= 1) {
        // ---- cvt + swizzled LDS write (compiler auto-waits on g) ----
        #pragma unroll
        for (int it = 0; it < 8; ++it) {
            int idx = tid + it * 512;
            int row = idx >> 8;
            int d = ((idx & 255) * 8) ^ ((row & 7) << 4);
            unsigned lo = (unsigned)f2bf(g[it][0]) | ((unsigned)f2bf(g[it][1]) << 16);
            unsigned hi = (unsigned)f2bf(g[it][2]) | ((unsigned)f2bf(g[it][3]) << 16);
            *(uint2*)((char*)(&As[p][0][0]) + row * 2048 + d) = make_uint2(lo, hi);
        }
        asm volatile("s_waitcnt lgkmcnt(0)" ::: "memory");
        __builtin_amdgcn_s_barrier();

        // ---- prefetch next tile into regs (in flight during compute) ----
        {
            long tn = tile + gridDim.x; if (tn >= tiles) tn = tile;
            #pragma unroll
            for (int it = 0; it < 8; ++it) {
                int idx = tid + it * 512;
                int row = idx >> 8;
                int c4 = (idx & 255) * 4; if (c4 > 956) c4 = 956;
                g[it] = *(const f32x4*)(x + (tn * 16 + row) * 960 + c4);
            }
        }

        const char* rb = (const char*)(&As[p][0][0]) + lr * 2048;
        float* ob = out + ((long)tile * 16 + q * 4) * 960;

        // ---- block0: l=0, K=256 (8 ks), 2 n-tiles/wave ----
        f32x4 acc0[2] = {};
        #pragma unroll
        for (int ks = 0; ks < 8; ++ks) {
            bf16x8 a = *(const bf16x8*)(rb + ((ks * 64 + q * 16) ^ sw));
            acc0[0] = mfma16(a, b0r[0][ks], acc0[0]);
            acc0[1] = mfma16(a, b0r[1][ks], acc0[1]);
        }
        #pragma unroll
        for (int i = 0; i < 2; ++i)
            #pragma unroll
            for (int j = 0; j < 4; ++j)
                ob[j * 960 + (2 * wv + i) * 16 + lr] = acc0[i][j];

        // ---- block1: l=1, K=128 (4 ks), 3 residues share one B-frag ----
        f32x4 acc1[3] = {};
        #pragma unroll
        for (int ks = 0; ks < 4; ++ks)
            #pragma unroll
            for (int r = 0; r < 3; ++r) {
                bf16x8 a = gatherA(rb, 512 + 192 * ks + 48 * q + 2 * r, sw, 6);
                acc1[r] = mfma16(a, b1r[ks], acc1[r]);
            }
        #pragma unroll
        for (int r = 0; r < 3; ++r)
            #pragma unroll
            for (int j = 0; j < 4; ++j)
                ob[j * 960 + 256 + wv * 48 + 3 * lr + r] = acc1[r][j];

        // ---- block2: l=2, K=64 (2 ks), residues split 3+2 across wave pairs ----
        f32x4 acc2[3] = {};
        #pragma unroll
        for (int ks = 0; ks < 2; ++ks)
            #pragma unroll
            for (int r = 0; r < 3; ++r)
                if (r < nR2) {
                    bf16x8 a = gatherA(rb, 1280 + 320 * ks + 80 * q + 2 * (rb2 + r), sw, 10);
                    acc2[r] = mfma16(a, b2r[ks], acc2[r]);
                }
        #pragma unroll
        for (int r = 0; r < 3; ++r)
            if (r < nR2)
                #pragma unroll
                for (int j = 0; j < 4; ++j)
                    ob[j * 960 + 640 + n1t2 * 80 + 5 * lr + rb2 + r] = acc2[r][j];
    }
}

extern "C" void kernel_launch(void* const* d_in, const int* in_sizes, int n_in,
                              void* d_out, int out_size, void* d_ws, size_t ws_size,
                              hipStream_t stream) {
    const float* x  = (const float*)d_in[0];
    const float* w0 = (const float*)d_in[1];
    const float* w1 = (const float*)d_in[2];
    const float* w2 = (const float*)d_in[3];
    float* out = (float*)d_out;
    u16t* wt = (u16t*)d_ws;   // 168 frags * 1 KB = 172 KB scratch

    const int N = in_sizes[0] / 960;

    pack_w<<<168, 64, 0, stream>>>(w0, w1, w2, wt);
    fused_linear<<<256, 512, 0, stream>>>(x, wt, out, N / 16);
}

// Round 6
// 338.402 us; speedup vs baseline: 1.5884x; 1.3816x over previous
//
#include <hip/hip_runtime.h>
#include <hip/hip_bf16.h>

typedef short bf16x8 __attribute__((ext_vector_type(8)));
typedef float f32x4 __attribute__((ext_vector_type(4)));
typedef unsigned short u16t;

__device__ __forceinline__ u16t f2bf(float f) {
    // plain cast -> v_cvt_pk_bf16_f32 pairs (RNE); compiler fuses adjacent pairs
    return __builtin_bit_cast(u16t, __float2bfloat16(f));
}

__device__ __forceinline__ f32x4 mfma16(bf16x8 a, bf16x8 b, f32x4 c) {
    return __builtin_amdgcn_mfma_f32_16x16x32_bf16(a, b, c, 0, 0, 0);
}

// Expanded transposed weight: wt[n'][k'] = (n'%D==k'%D) ? w[k'/D][n'/D]*scale : 0
// (B' = W (x) I_D : GEMM N'/K' are the raw interleaved channel indices ->
//  linear A staging, stores in native channel order.)
template<int D, int MUL>
__global__ void expand_w(const float* __restrict__ w, u16t* __restrict__ wt, float scale) {
    const int n = blockIdx.x;      // 0..MUL*D-1
    const int k = threadIdx.x;     // 0..MUL*D-1
    float v = 0.0f;
    if (D == 1 || (n % D) == (k % D))
        v = w[(k / D) * MUL + (n / D)] * scale;
    wt[n * (MUL * D) + k] = f2bf(v);
}

// One nt-half: K-outer loop, A from swizzled LDS (b128), B' from L2, acc[4][NTH],
// direct stores (wave span per row = NTH*64B contiguous -> full 128B lines).
template<int KP, int NTH>
__device__ __forceinline__ void compute_half(const char* __restrict__ arow,
                                             const u16t* __restrict__ wb,
                                             float* __restrict__ orow,
                                             int nt0, int lr, int q) {
    constexpr int KS = KP / 32;
    f32x4 acc[4][NTH] = {};
    #pragma unroll
    for (int ks = 0; ks < KS; ++ks) {
        bf16x8 b[NTH];
        #pragma unroll
        for (int nt = 0; nt < NTH; ++nt)
            b[nt] = *(const bf16x8*)(wb + ((nt0 + nt) * 16 + lr) * KP + ks * 32 + q * 8);
        #pragma unroll
        for (int mt = 0; mt < 4; ++mt) {
            bf16x8 a = *(const bf16x8*)(arow + mt * 16 * KP * 2 +
                                        ((ks * 64 + q * 16) ^ ((lr & 7) << 4)));
            #pragma unroll
            for (int nt = 0; nt < NTH; ++nt)
                acc[mt][nt] = mfma16(a, b[nt], acc[mt][nt]);
        }
    }
    #pragma unroll
    for (int mt = 0; mt < 4; ++mt)
        #pragma unroll
        for (int nt = 0; nt < NTH; ++nt)
            #pragma unroll
            for (int j = 0; j < 4; ++j)
                orow[(mt * 16 + q * 4 + j) * 960 + (nt0 + nt) * 16 + lr] = acc[mt][nt][j];
}

// One WG (256 thr / 4 waves) = one irrep block x one 64-row tile.
template<int KP, int OFF, int NTH0, int NTH1>
__device__ __forceinline__ void do_block(const float* __restrict__ x,
                                         const u16t* __restrict__ wb,
                                         float* __restrict__ out,
                                         char* smem, long tile, int tid) {
    constexpr int C8  = KP / 8;            // 16B bf16 chunks per row
    constexpr int NCH = 64 * C8 / 256;     // chunks per thread
    constexpr int NTW = NTH0 + NTH1;       // n-tiles per wave
    const int lane = tid & 63, wv = tid >> 6, lr = lane & 15, q = lane >> 4;
    const float* xr = x + tile * 64 * 960 + OFF;
    float* orow = out + tile * 64 * 960 + OFF;

    // ---- stage: 64 x KP fp32 (contiguous) -> bf16 -> XOR-swizzled LDS ----
    #pragma unroll
    for (int it = 0; it < NCH; ++it) {
        int idx = tid + it * 256;
        int row = idx / C8;
        int c8  = idx % C8;
        const float* p = xr + row * 960 + c8 * 8;
        f32x4 v0 = *(const f32x4*)p;
        f32x4 v1 = *(const f32x4*)(p + 4);
        bf16x8 sv;
        sv[0] = f2bf(v0[0]); sv[1] = f2bf(v0[1]); sv[2] = f2bf(v0[2]); sv[3] = f2bf(v0[3]);
        sv[4] = f2bf(v1[0]); sv[5] = f2bf(v1[1]); sv[6] = f2bf(v1[2]); sv[7] = f2bf(v1[3]);
        *(bf16x8*)(smem + row * (KP * 2) + ((c8 * 16) ^ ((row & 7) << 4))) = sv;
    }
    __syncthreads();

    const char* arow = smem + lr * (KP * 2);
    compute_half<KP, NTH0>(arow, wb, orow, wv * NTW,        lr, q);
    compute_half<KP, NTH1>(arow, wb, orow, wv * NTW + NTH0, lr, q);
}

// blockIdx % 3 selects irrep block -> each CU hosts mixed-type, mixed-phase WGs.
__global__ __launch_bounds__(256, 3)
void fused_linear(const float* __restrict__ x, const u16t* __restrict__ wt,
                  float* __restrict__ out) {
    __shared__ __align__(16) char smem[64 * 384 * 2];   // 48 KB (block1 size)
    const long gid  = blockIdx.x;
    const int  bt   = (int)(gid % 3);
    const long tile = gid / 3;
    const int  tid  = threadIdx.x;
    if (bt == 0)      do_block<256,   0, 2, 2>(x, wt,          out, smem, tile, tid);
    else if (bt == 1) do_block<384, 256, 3, 3>(x, wt +  65536, out, smem, tile, tid);
    else              do_block<320, 640, 3, 2>(x, wt + 212992, out, smem, tile, tid);
}

extern "C" void kernel_launch(void* const* d_in, const int* in_sizes, int n_in,
                              void* d_out, int out_size, void* d_ws, size_t ws_size,
                              hipStream_t stream) {
    const float* x  = (const float*)d_in[0];
    const float* w0 = (const float*)d_in[1];
    const float* w1 = (const float*)d_in[2];
    const float* w2 = (const float*)d_in[3];
    float* out = (float*)d_out;
    u16t* wt = (u16t*)d_ws;   // 315392 u16 = 616 KB scratch

    const int N     = in_sizes[0] / 960;
    const int tiles = N / 64;

    expand_w<1, 256><<<256, 256, 0, stream>>>(w0, wt,          0.0625f);
    expand_w<3, 128><<<384, 384, 0, stream>>>(w1, wt +  65536, 0.08838834764831845f);
    expand_w<5,  64><<<320, 320, 0, stream>>>(w2, wt + 212992, 0.125f);

    fused_linear<<<3 * tiles, 256, 0, stream>>>(x, wt, out);
}